// Round 12
// baseline (327.779 us; speedup 1.0000x reference)
//
#include <hip/hip_runtime.h>

// LinkPrediction: per-edge 2-layer MLP routed by edge type (MoE-style).
// outputs: [0..N_EDGES) = scores, [N_EDGES..) = copy of rgcn_emb.
//
// R15. Theory: score is TA/L1 TRANSACTION bound. lane=edge gathers make every
// wave load touch 64 distinct lines (~64 L1 line-cycles/instr); 32/row.
// Evidence: 112-118us invariant to chain depth (R6 8-round=118, R14 4-round
// =112) and wave count; f16 (half the chunks) = 86us; no pipe >41%.
// Fix: coalesced LDS tiles, occupancy-safe (R8 redux: R8 died on 64KB LDS ->
// 2 blk/CU + no overlap):
//   EB=64 edges/block, 32KB LDS -> 5 blocks/CU (cross-block overlap).
//   Stage: 32 contiguous lanes per 512B row -> 1 instr = 2 rows = 8 lines
//   (8x fewer L1 line-cycles). Rotate swizzle (c+row)&31: write & read at
//   bank-bandwidth floor. Compute: wave w = dim-quarter w (W1 scalar,
//   wave-uniform), lane=row reads uniform chunk column from LDS.
//   2 phases (src,dst) -> one acc[24]; partial join in same buffer.
// scatter pads types to 64 (block type-purity). Copy trailing (proven free).

typedef float f4 __attribute__((ext_vector_type(4)));

constexpr int N_NODES = 200000;
constexpr int N_EDGES = 400000;
constexpr int EMB_DIM = 128;
constexpr int HID     = 24;
constexpr int N_TYPES = 8;
constexpr int BLK     = 256;

constexpr int CHUNKS  = 128;
constexpr int CH_SZ   = N_EDGES / CHUNKS;                  // 3125 exact
constexpr int MAX_PAD = N_EDGES + N_TYPES * (BLK - 1);     // ws sizing (superset)

constexpr int EB = 64;                                      // edges per score block
constexpr int MAX_PAD64 = N_EDGES + N_TYPES * (EB - 1);     // 400504
constexpr int SCORE_BLOCKS = (MAX_PAD64 + EB - 1) / EB;     // 6258
constexpr int COPY_BLOCKS  = 1024;

// ws int offsets
constexpr int OFF_CC     = 0;                               // [CHUNKS*8]
constexpr int OFF_COUNTS = OFF_CC + CHUNKS * N_TYPES;       // [8]
constexpr int OFF_POFF   = OFF_COUNTS + N_TYPES;            // [8]
constexpr int OFF_SORTED = OFF_POFF + N_TYPES;              // [MAX_PAD]
constexpr size_t WS_NEED = (size_t)(OFF_SORTED + MAX_PAD) * sizeof(int);

// ---------- K1: per-chunk histogram (no global atomics, no memset) ----------
__global__ __launch_bounds__(BLK) void hist_k(const int* __restrict__ etype,
                                              int* __restrict__ ws) {
    __shared__ int lc[N_TYPES];
    int b = blockIdx.x;
    if (threadIdx.x < N_TYPES) lc[threadIdx.x] = 0;
    __syncthreads();
    int e0 = b * CH_SZ;
    for (int e = e0 + (int)threadIdx.x; e < e0 + CH_SZ; e += BLK)
        atomicAdd(&lc[etype[e]], 1);
    __syncthreads();
    if (threadIdx.x < N_TYPES)
        ws[OFF_CC + b * N_TYPES + threadIdx.x] = lc[threadIdx.x];
}

// ---------- K2: deterministic scan + scatter (64-pad per type) ----------
__global__ __launch_bounds__(BLK) void scatter_k(
        const int* __restrict__ etype, int* __restrict__ ws) {
    __shared__ int sbase[N_TYPES];
    __shared__ int tot[N_TYPES];
    __shared__ int mybase[N_TYPES];
    __shared__ int spoff[N_TYPES];
    __shared__ int lc[N_TYPES];
    int b = blockIdx.x;
    if (threadIdx.x < N_TYPES) {
        int t = threadIdx.x, s = 0, mb = 0;
        for (int c = 0; c < CHUNKS; ++c) {
            if (c == b) mb = s;
            s += ws[OFF_CC + c * N_TYPES + t];
        }
        tot[t] = s;
        mybase[t] = mb;
        lc[t] = 0;
    }
    __syncthreads();
    if (threadIdx.x == 0) {
        int off = 0;
        for (int t = 0; t < N_TYPES; ++t) {
            spoff[t] = off;
            off += ((tot[t] + EB - 1) / EB) * EB;           // 64-pad per type
        }
    }
    __syncthreads();
    if (threadIdx.x < N_TYPES) {
        sbase[threadIdx.x] = spoff[threadIdx.x] + mybase[threadIdx.x];
        if (b == 0) {
            ws[OFF_COUNTS + threadIdx.x] = tot[threadIdx.x];
            ws[OFF_POFF + threadIdx.x]   = spoff[threadIdx.x];
        }
    }
    __syncthreads();
    int e0 = b * CH_SZ;
    int* sorted = ws + OFF_SORTED;
    for (int e = e0 + (int)threadIdx.x; e < e0 + CH_SZ; e += BLK) {
        int t = etype[e];
        int r = atomicAdd(&lc[t], 1);                       // LDS-local only
        sorted[sbase[t] + r] = e;
    }
}

// ---------- K3: LDS-tiled coalesced score + fused copy ----------
__device__ __forceinline__ void do_copy(const float* __restrict__ emb,
                                        float* __restrict__ out, int cb, int nb) {
    const f4* s4 = (const f4*)emb;
    f4* o4 = (f4*)(out + N_EDGES);
    const int n4 = N_NODES * EMB_DIM / 4;                   // 6.4M
    for (int i = cb * BLK + (int)threadIdx.x; i < n4; i += nb * BLK) {
        f4 a = s4[i];                                       // normal: warms LLC
        __builtin_nontemporal_store(a, &o4[i]);             // never re-read
    }
}

__global__ __launch_bounds__(BLK) void score_tile_k(
        const float* __restrict__ emb,
        const int* __restrict__ srci, const int* __restrict__ dsti,
        const int* __restrict__ ws,
        const float* __restrict__ W1, const float* __restrict__ b1,
        const float* __restrict__ W2, const float* __restrict__ b2,
        float* __restrict__ out) {
    __shared__ float lds[EB * EMB_DIM];                     // 32 KB
    int b = blockIdx.x;
    if (b >= SCORE_BLOCKS) {
        do_copy(emb, out, b - SCORE_BLOCKS, (int)gridDim.x - SCORE_BLOCKS);
        return;
    }
    int poff[N_TYPES], counts[N_TYPES];
#pragma unroll
    for (int t = 0; t < N_TYPES; ++t) {
        counts[t] = ws[OFF_COUNTS + t];
        poff[t]   = ws[OFF_POFF + t];
    }
    int off = poff[N_TYPES - 1] + ((counts[N_TYPES - 1] + EB - 1) / EB) * EB;
    const int slot0 = b * EB;
    if (slot0 >= off) return;                               // uniform: safe
    int t = 0;
#pragma unroll
    for (int i = 1; i < N_TYPES; ++i)
        if (slot0 >= poff[i]) t = i;
    t = __builtin_amdgcn_readfirstlane(t);                  // block-uniform type
    const int cnt = counts[t];
    const int tbase = poff[t];
    const int* sorted = ws + OFF_SORTED;

    const int tid  = (int)threadIdx.x;
    const int l    = tid & 63;                              // compute: row 0..63
    const int w    = __builtin_amdgcn_readfirstlane(tid >> 6);  // dim-quarter 0..3
    const int srow = tid >> 5;                              // stage: row offset 0..7
    const int scol = tid & 31;                              // stage: f4 chunk 0..31
    const float* W1t = W1 + (size_t)t * (2 * EMB_DIM * HID);
    f4* ldsf4 = (f4*)lds;
    const f4* embf4 = (const f4*)emb;

    float acc[HID];
#pragma unroll
    for (int j = 0; j < HID; ++j) acc[j] = 0.f;

#pragma unroll 1
    for (int phase = 0; phase < 2; ++phase) {
        const int* __restrict__ nodes = phase ? dsti : srci;
        if (phase) __syncthreads();                         // buffer reusable
        // ---- stage: 32 contiguous lanes per row -> 2 rows (8 lines)/instr ----
#pragma unroll
        for (int j = 0; j < 8; ++j) {
            int row  = j * 8 + srow;
            int slot = slot0 + row;
            int e    = sorted[((slot - tbase) < cnt) ? slot : tbase];
            int nd   = nodes[e];
            ldsf4[row * 32 + ((scol + row) & 31)] = embf4[(size_t)nd * 32 + scol];
        }
        __syncthreads();
        // ---- compute: wave w = dims w*32..w*32+31 of row l (W1 scalar) ----
        const float* wp0 = W1t + (size_t)(phase * EMB_DIM + w * 32) * HID;
#pragma unroll
        for (int k = 0; k < 8; ++k) {
            int C = w * 8 + k;
            f4 rv = ldsf4[l * 32 + ((C + l) & 31)];
            const float* wp = wp0 + (k * 4) * HID;
#pragma unroll
            for (int j = 0; j < HID; ++j) acc[j] = fmaf(rv[0], wp[0 * HID + j], acc[j]);
#pragma unroll
            for (int j = 0; j < HID; ++j) acc[j] = fmaf(rv[1], wp[1 * HID + j], acc[j]);
#pragma unroll
            for (int j = 0; j < HID; ++j) acc[j] = fmaf(rv[2], wp[2 * HID + j], acc[j]);
#pragma unroll
            for (int j = 0; j < HID; ++j) acc[j] = fmaf(rv[3], wp[3 * HID + j], acc[j]);
        }
    }

    // ---- join quarters: waves 1-3 publish, wave 0 reduces + epilogue ----
    __syncthreads();                                        // compute done, reuse lds
    if (w != 0) {
#pragma unroll
        for (int j = 0; j < HID; ++j) lds[(l * 4 + w) * 25 + j] = acc[j];
    }
    __syncthreads();
    if (w == 0) {
        int slot = slot0 + l;
        if ((slot - tbase) < cnt) {
            int e = sorted[slot];
            float sc = b2[t];
#pragma unroll
            for (int j = 0; j < HID; ++j) {
                float h = acc[j] + lds[(l * 4 + 1) * 25 + j]
                                 + lds[(l * 4 + 2) * 25 + j]
                                 + lds[(l * 4 + 3) * 25 + j]
                                 + b1[t * HID + j];
                h = (h > 0.f) ? h : 0.01f * h;              // LeakyReLU(0.01)
                sc = fmaf(h, W2[t * HID + j], sc);
            }
            out[e] = sc;
        }
    }
}

// ---------- ws-too-small fallback: correctness only ----------
__global__ __launch_bounds__(BLK) void fallback_k(
        const float* __restrict__ emb,
        const int* __restrict__ srci, const int* __restrict__ dsti,
        const int* __restrict__ etype,
        const float* __restrict__ W1, const float* __restrict__ b1,
        const float* __restrict__ W2, const float* __restrict__ b2,
        float* __restrict__ out) {
    long long i0 = (long long)blockIdx.x * BLK + threadIdx.x;
    const f4* s4 = (const f4*)emb;
    f4* o4 = (f4*)(out + N_EDGES);
    const long long n4 = (long long)N_NODES * EMB_DIM / 4;
    for (long long i = i0; i < n4; i += (long long)gridDim.x * BLK)
        o4[i] = s4[i];
    for (int e = (int)i0; e < N_EDGES; e += gridDim.x * BLK) {
        int t = etype[e];
        int s = srci[e], d = dsti[e];
        float acc[HID];
#pragma unroll
        for (int j = 0; j < HID; ++j) acc[j] = b1[t * HID + j];
        const float* wb = W1 + (size_t)t * 2 * EMB_DIM * HID;
        for (int k = 0; k < EMB_DIM; ++k) {
            float x = emb[(size_t)s * EMB_DIM + k];
#pragma unroll
            for (int j = 0; j < HID; ++j) acc[j] = fmaf(x, wb[k * HID + j], acc[j]);
        }
        for (int k = 0; k < EMB_DIM; ++k) {
            float x = emb[(size_t)d * EMB_DIM + k];
#pragma unroll
            for (int j = 0; j < HID; ++j) acc[j] = fmaf(x, wb[(EMB_DIM + k) * HID + j], acc[j]);
        }
        float sc = b2[t];
#pragma unroll
        for (int j = 0; j < HID; ++j) {
            float h = acc[j];
            h = (h > 0.f) ? h : 0.01f * h;
            sc = fmaf(h, W2[t * HID + j], sc);
        }
        out[e] = sc;
    }
}

extern "C" void kernel_launch(void* const* d_in, const int* in_sizes, int n_in,
                              void* d_out, int out_size, void* d_ws, size_t ws_size,
                              hipStream_t stream) {
    const float* emb   = (const float*)d_in[0];
    const int*   eidx  = (const int*)d_in[1];
    const int*   etype = (const int*)d_in[2];
    const float* W1    = (const float*)d_in[3];
    const float* b1    = (const float*)d_in[4];
    const float* W2    = (const float*)d_in[5];
    const float* b2    = (const float*)d_in[6];
    float* out = (float*)d_out;
    const int* srci = eidx;
    const int* dsti = eidx + N_EDGES;

    if (ws_size >= WS_NEED) {
        int* ws = (int*)d_ws;
        hist_k<<<CHUNKS, BLK, 0, stream>>>(etype, ws);
        scatter_k<<<CHUNKS, BLK, 0, stream>>>(etype, ws);
        score_tile_k<<<SCORE_BLOCKS + COPY_BLOCKS, BLK, 0, stream>>>(
            emb, srci, dsti, ws, W1, b1, W2, b2, out);
    } else {
        fallback_k<<<2048, BLK, 0, stream>>>(emb, srci, dsti, etype, W1, b1, W2, b2, out);
    }
}

// Round 13
// 272.549 us; speedup vs baseline: 1.2026x; 1.2026x over previous
//
#include <hip/hip_runtime.h>

// LinkPrediction: per-edge 2-layer MLP routed by edge type (MoE-style).
// outputs: [0..N_EDGES) = scores, [N_EDGES..) = copy of rgcn_emb.
//
// R16: MFMA score kernel. Empirical law from R0-R15: gather cost ~= 1
// line-request/cy/CU; lane=edge layouts touch 64 lines/instr (fp32: 25.6M
// req ~42us; f16: ~21us; base ~70us). Scalar-weight VALU kernels CANNOT
// reduce lines/instr (uniform-dim walk forces lane=edge). MFMA fragments
// CAN: 4 lanes share a row's 128B line per A/X load (16 lines/instr, 4x
// fewer requests ~10us) and the 31us VALU floor -> ~2us of matrix pipe.
// Per wave: D[hid(24->32)][edge16] = sum_s Wfrag[32xhid] * Xfrag[edge x32],
// 8 K-steps x 2 hid-tiles = 16 mfma_f32_16x16x32_f16. W-frags: 16 x h8 regs,
// reloaded only on type change (block owns 4 contiguous 64-edge groups of
// the type-sorted order). Epilogue: +b1, LeakyReLU, xW2, shfl_xor(16,32).
// No LDS, no barriers. f16 in / f32 accum (R0's f16 passed absmax 0.0039).
//  K1 hist_k / K2 scatter_k (64-pad): proven ~13us. Copy trailing (free).

typedef float    f4   __attribute__((ext_vector_type(4)));
typedef _Float16 h8   __attribute__((ext_vector_type(8)));
typedef float    f32x4 __attribute__((ext_vector_type(4)));

constexpr int N_NODES = 200000;
constexpr int N_EDGES = 400000;
constexpr int EMB_DIM = 128;
constexpr int HID     = 24;
constexpr int N_TYPES = 8;
constexpr int BLK     = 256;

constexpr int CHUNKS  = 128;
constexpr int CH_SZ   = N_EDGES / CHUNKS;                  // 3125 exact
constexpr int MAX_PAD = N_EDGES + N_TYPES * (BLK - 1);     // ws sizing (superset)

constexpr int EB        = 64;                               // edges per group
constexpr int MAX_PAD64 = N_EDGES + N_TYPES * (EB - 1);     // 400504
constexpr int NGRP      = (MAX_PAD64 + EB - 1) / EB;        // 6258
constexpr int GPB       = 4;                                // groups per block
constexpr int SCORE_MB  = (NGRP + GPB - 1) / GPB;           // 1565
constexpr int COPY_BLOCKS = 1024;

// ws int offsets
constexpr int OFF_CC     = 0;                               // [CHUNKS*8]
constexpr int OFF_COUNTS = OFF_CC + CHUNKS * N_TYPES;       // [8]
constexpr int OFF_POFF   = OFF_COUNTS + N_TYPES;            // [8]
constexpr int OFF_SORTED = OFF_POFF + N_TYPES;              // [MAX_PAD]
constexpr size_t WS_NEED = (size_t)(OFF_SORTED + MAX_PAD) * sizeof(int);

// ---------- K1: per-chunk histogram (no global atomics, no memset) ----------
__global__ __launch_bounds__(BLK) void hist_k(const int* __restrict__ etype,
                                              int* __restrict__ ws) {
    __shared__ int lc[N_TYPES];
    int b = blockIdx.x;
    if (threadIdx.x < N_TYPES) lc[threadIdx.x] = 0;
    __syncthreads();
    int e0 = b * CH_SZ;
    for (int e = e0 + (int)threadIdx.x; e < e0 + CH_SZ; e += BLK)
        atomicAdd(&lc[etype[e]], 1);
    __syncthreads();
    if (threadIdx.x < N_TYPES)
        ws[OFF_CC + b * N_TYPES + threadIdx.x] = lc[threadIdx.x];
}

// ---------- K2: deterministic scan + scatter (64-pad per type) ----------
__global__ __launch_bounds__(BLK) void scatter_k(
        const int* __restrict__ etype, int* __restrict__ ws) {
    __shared__ int sbase[N_TYPES];
    __shared__ int tot[N_TYPES];
    __shared__ int mybase[N_TYPES];
    __shared__ int spoff[N_TYPES];
    __shared__ int lc[N_TYPES];
    int b = blockIdx.x;
    if (threadIdx.x < N_TYPES) {
        int t = threadIdx.x, s = 0, mb = 0;
        for (int c = 0; c < CHUNKS; ++c) {
            if (c == b) mb = s;
            s += ws[OFF_CC + c * N_TYPES + t];
        }
        tot[t] = s;
        mybase[t] = mb;
        lc[t] = 0;
    }
    __syncthreads();
    if (threadIdx.x == 0) {
        int off = 0;
        for (int t = 0; t < N_TYPES; ++t) {
            spoff[t] = off;
            off += ((tot[t] + EB - 1) / EB) * EB;           // 64-pad per type
        }
    }
    __syncthreads();
    if (threadIdx.x < N_TYPES) {
        sbase[threadIdx.x] = spoff[threadIdx.x] + mybase[threadIdx.x];
        if (b == 0) {
            ws[OFF_COUNTS + threadIdx.x] = tot[threadIdx.x];
            ws[OFF_POFF + threadIdx.x]   = spoff[threadIdx.x];
        }
    }
    __syncthreads();
    int e0 = b * CH_SZ;
    int* sorted = ws + OFF_SORTED;
    for (int e = e0 + (int)threadIdx.x; e < e0 + CH_SZ; e += BLK) {
        int t = etype[e];
        int r = atomicAdd(&lc[t], 1);                       // LDS-local only
        sorted[sbase[t] + r] = e;
    }
}

// ---------- K3: MFMA score + fused copy ----------
__device__ __forceinline__ void do_copy(const float* __restrict__ emb,
                                        float* __restrict__ out, int cb, int nb) {
    const f4* s4 = (const f4*)emb;
    f4* o4 = (f4*)(out + N_EDGES);
    const int n4 = N_NODES * EMB_DIM / 4;                   // 6.4M
    for (int i = cb * BLK + (int)threadIdx.x; i < n4; i += nb * BLK) {
        f4 a = s4[i];                                       // normal: warms LLC
        __builtin_nontemporal_store(a, &o4[i]);             // never re-read
    }
}

__global__ __launch_bounds__(BLK) void score_mfma_k(
        const float* __restrict__ emb,
        const int* __restrict__ srci, const int* __restrict__ dsti,
        const int* __restrict__ ws,
        const float* __restrict__ W1, const float* __restrict__ b1,
        const float* __restrict__ W2, const float* __restrict__ b2,
        float* __restrict__ out) {
    int b = blockIdx.x;
    if (b >= SCORE_MB) {
        do_copy(emb, out, b - SCORE_MB, (int)gridDim.x - SCORE_MB);
        return;
    }
    int poff[N_TYPES], counts[N_TYPES];
#pragma unroll
    for (int t = 0; t < N_TYPES; ++t) {
        counts[t] = ws[OFF_COUNTS + t];
        poff[t]   = ws[OFF_POFF + t];
    }
    const int off = poff[N_TYPES - 1]
                  + ((counts[N_TYPES - 1] + EB - 1) / EB) * EB;
    const int* sorted = ws + OFF_SORTED;

    const int tid = (int)threadIdx.x;
    const int l   = tid & 63;
    const int w   = tid >> 6;                               // wave 0..3
    const int lm  = l & 15;                                 // edge idx / W-col
    const int lg  = l >> 4;                                 // k-group / hid-group

    h8 wf[16];                                              // W frags [s*2+m]
    float b1v0[4], w2v0[4], b1v1[4], w2v1[4];
    float b2t = 0.f;
    int cur_t = -1, tbase = 0, cnt = 0;

#pragma unroll 1
    for (int g = b * GPB; g < (b + 1) * GPB && g < NGRP; ++g) {
        const int slot0g = g * EB;
        if (slot0g >= off) break;
        int t = 0;
#pragma unroll
        for (int i = 1; i < N_TYPES; ++i)
            if (slot0g >= poff[i]) t = i;
        t = __builtin_amdgcn_readfirstlane(t);              // group-uniform
        if (t != cur_t) {                                   // reload W frags
            cur_t = t;
            tbase = poff[t];
            cnt   = counts[t];
            const float* W1t = W1 + (size_t)t * (2 * EMB_DIM * HID);
#pragma unroll
            for (int s = 0; s < 8; ++s) {
#pragma unroll
                for (int m = 0; m < 2; ++m) {
                    const int colh = m * 16 + lm;           // hid col 0..31
                    const float* wp = W1t + (size_t)(32 * s + lg * 8) * HID + colh;
                    h8 f;
                    if (colh < HID) {
#pragma unroll
                        for (int i = 0; i < 8; ++i) f[i] = (_Float16)wp[i * HID];
                    } else {
#pragma unroll
                        for (int i = 0; i < 8; ++i) f[i] = (_Float16)0.f;
                    }
                    wf[s * 2 + m] = f;
                }
            }
#pragma unroll
            for (int i = 0; i < 4; ++i) {
                const int j0 = lg * 4 + i;                  // hid 0..15
                b1v0[i] = b1[t * HID + j0];
                w2v0[i] = W2[t * HID + j0];
                const int j1 = 16 + j0;                     // hid 16..31
                const bool v1 = j1 < HID;
                b1v1[i] = v1 ? b1[t * HID + j1] : 0.f;
                w2v1[i] = v1 ? W2[t * HID + j1] : 0.f;
            }
            b2t = b2[t];
        }
        if (cnt == 0) continue;
        const int slot_w = slot0g + w * 16;
        const int slot   = slot_w + lm;
        const bool evalid = (slot - tbase) < cnt;
        const int e  = sorted[evalid ? slot : tbase];
        const int ns = srci[e], nd = dsti[e];

        f32x4 acc0 = {0.f, 0.f, 0.f, 0.f};
        f32x4 acc1 = {0.f, 0.f, 0.f, 0.f};
#pragma unroll
        for (int s = 0; s < 8; ++s) {
            // X frag: edge lm, dims 32s..32s+31; lane covers 8 consecutive.
            const float* xr = emb + (size_t)(s < 4 ? ns : nd) * EMB_DIM
                            + (s & 3) * 32 + lg * 8;
            f4 lo = *(const f4*)xr;
            f4 hi = *(const f4*)(xr + 4);
            h8 xb;
            xb[0] = (_Float16)lo[0]; xb[1] = (_Float16)lo[1];
            xb[2] = (_Float16)lo[2]; xb[3] = (_Float16)lo[3];
            xb[4] = (_Float16)hi[0]; xb[5] = (_Float16)hi[1];
            xb[6] = (_Float16)hi[2]; xb[7] = (_Float16)hi[3];
            acc0 = __builtin_amdgcn_mfma_f32_16x16x32_f16(wf[s * 2 + 0], xb, acc0, 0, 0, 0);
            acc1 = __builtin_amdgcn_mfma_f32_16x16x32_f16(wf[s * 2 + 1], xb, acc1, 0, 0, 0);
        }
        // D: row = hid lg*4+i (+16 for acc1), col = edge lm.
        float v = 0.f;
#pragma unroll
        for (int i = 0; i < 4; ++i) {
            float h0 = acc0[i] + b1v0[i];
            h0 = (h0 > 0.f) ? h0 : 0.01f * h0;              // LeakyReLU(0.01)
            v = fmaf(h0, w2v0[i], v);
            float h1 = acc1[i] + b1v1[i];                   // zero rows -> 0
            h1 = (h1 > 0.f) ? h1 : 0.01f * h1;
            v = fmaf(h1, w2v1[i], v);
        }
        v += __shfl_xor(v, 16);                             // sum hid-groups
        v += __shfl_xor(v, 32);
        if (l < 16 && evalid)                               // lane l = edge l
            out[e] = v + b2t;
    }
}

// ---------- ws-too-small fallback: correctness only ----------
__global__ __launch_bounds__(BLK) void fallback_k(
        const float* __restrict__ emb,
        const int* __restrict__ srci, const int* __restrict__ dsti,
        const int* __restrict__ etype,
        const float* __restrict__ W1, const float* __restrict__ b1,
        const float* __restrict__ W2, const float* __restrict__ b2,
        float* __restrict__ out) {
    long long i0 = (long long)blockIdx.x * BLK + threadIdx.x;
    const f4* s4 = (const f4*)emb;
    f4* o4 = (f4*)(out + N_EDGES);
    const long long n4 = (long long)N_NODES * EMB_DIM / 4;
    for (long long i = i0; i < n4; i += (long long)gridDim.x * BLK)
        o4[i] = s4[i];
    for (int e = (int)i0; e < N_EDGES; e += gridDim.x * BLK) {
        int t = etype[e];
        int s = srci[e], d = dsti[e];
        float acc[HID];
#pragma unroll
        for (int j = 0; j < HID; ++j) acc[j] = b1[t * HID + j];
        const float* wb = W1 + (size_t)t * 2 * EMB_DIM * HID;
        for (int k = 0; k < EMB_DIM; ++k) {
            float x = emb[(size_t)s * EMB_DIM + k];
#pragma unroll
            for (int j = 0; j < HID; ++j) acc[j] = fmaf(x, wb[k * HID + j], acc[j]);
        }
        for (int k = 0; k < EMB_DIM; ++k) {
            float x = emb[(size_t)d * EMB_DIM + k];
#pragma unroll
            for (int j = 0; j < HID; ++j) acc[j] = fmaf(x, wb[(EMB_DIM + k) * HID + j], acc[j]);
        }
        float sc = b2[t];
#pragma unroll
        for (int j = 0; j < HID; ++j) {
            float h = acc[j];
            h = (h > 0.f) ? h : 0.01f * h;
            sc = fmaf(h, W2[t * HID + j], sc);
        }
        out[e] = sc;
    }
}

extern "C" void kernel_launch(void* const* d_in, const int* in_sizes, int n_in,
                              void* d_out, int out_size, void* d_ws, size_t ws_size,
                              hipStream_t stream) {
    const float* emb   = (const float*)d_in[0];
    const int*   eidx  = (const int*)d_in[1];
    const int*   etype = (const int*)d_in[2];
    const float* W1    = (const float*)d_in[3];
    const float* b1    = (const float*)d_in[4];
    const float* W2    = (const float*)d_in[5];
    const float* b2    = (const float*)d_in[6];
    float* out = (float*)d_out;
    const int* srci = eidx;
    const int* dsti = eidx + N_EDGES;

    if (ws_size >= WS_NEED) {
        int* ws = (int*)d_ws;
        hist_k<<<CHUNKS, BLK, 0, stream>>>(etype, ws);
        scatter_k<<<CHUNKS, BLK, 0, stream>>>(etype, ws);
        score_mfma_k<<<SCORE_MB + COPY_BLOCKS, BLK, 0, stream>>>(
            emb, srci, dsti, ws, W1, b1, W2, b2, out);
    } else {
        fallback_k<<<2048, BLK, 0, stream>>>(emb, srci, dsti, etype, W1, b1, W2, b2, out);
    }
}